// Round 1
// baseline (281.603 us; speedup 1.0000x reference)
//
#include <hip/hip_runtime.h>

#define B_TOTAL 2000000
#define PAD 21  // 21 coprime with 32 banks -> conflict-free LDS writes in transpose phase

// POLLU RHS: 25 fluxes, 20 species, stoichiometry hard-coded.
// conc: [20, B] species-major; out: [B, 20].
// v2: input staged via global_load_lds (16B/lane async DMA, one instr per
//     species row per block) into a linear [20][256] LDS tile, unioned with
//     the padded out-transpose tile. Stores unchanged (dense float4 sweep).
__global__ __launch_bounds__(256) void pollu_kernel(
    const float* __restrict__ conc,
    const float* __restrict__ k,
    float* __restrict__ out)
{
    __shared__ float sk[25];
    // Union: in-tile = floats [0, 20*256) linear; out-tile = [256][PAD] = 5376 floats.
    __shared__ float lds[256 * PAD];  // 21504 B -> 7 blocks/CU

    const int t = threadIdx.x;
    const int blockStart = blockIdx.x * 256;
    const int b = blockStart + t;
    const int nvalid = min(256, B_TOTAL - blockStart);
    const bool fullBlock = (nvalid == 256);

    if (t < 25) sk[t] = k[t];

    float c[20];

    if (fullBlock) {
        // Async global->LDS: each wave stages 5 species rows; one
        // global_load_lds_dwordx4 covers exactly one row (64 lanes x 16B = 1024B).
        const int wave = t >> 6;
        const int lane = t & 63;
#pragma unroll
        for (int i = 0; i < 5; ++i) {
            const int s = wave * 5 + i;
            const float* src = conc + (size_t)s * (size_t)B_TOTAL
                                    + (size_t)blockStart + (size_t)(lane * 4);
            __builtin_amdgcn_global_load_lds(
                (const __attribute__((address_space(1))) uint32_t*)src,
                (__attribute__((address_space(3))) uint32_t*)(&lds[s * 256]),
                16, 0, 0);
        }
        __syncthreads();  // compiler drains vmcnt (staging) + lgkmcnt (sk) here

        // Column read: addr = s*256 + t -> consecutive lanes hit consecutive
        // banks; 2 lanes/bank over wave64 is free. No pad needed (and gload_lds
        // forbids one anyway).
#pragma unroll
        for (int s = 0; s < 20; ++s) c[s] = lds[s * 256 + t];
        __syncthreads();  // all in-tile reads done before out-tile overwrites it
    } else {
        __syncthreads();  // sk visible (block-uniform branch: barrier counts may differ per path)
#pragma unroll
        for (int s = 0; s < 20; ++s) c[s] = 0.0f;
        if (b < B_TOTAL) {
#pragma unroll
            for (int s = 0; s < 20; ++s) c[s] = conc[(size_t)s * B_TOTAL + (size_t)b];
        }
    }

    // flux r = k[r] * C[a_r] * C[b_r]  (index 20 == constant 1.0 row)
    const float f1  = sk[0]  * c[0];
    const float f2  = sk[1]  * c[1]  * c[3];
    const float f3  = sk[2]  * c[4]  * c[1];
    const float f4  = sk[3]  * c[6];
    const float f5  = sk[4]  * c[6];
    const float f6  = sk[5]  * c[6]  * c[5];
    const float f7  = sk[6]  * c[8];
    const float f8  = sk[7]  * c[8]  * c[5];
    const float f9  = sk[8]  * c[10] * c[1];
    const float f10 = sk[9]  * c[10] * c[0];
    const float f11 = sk[10] * c[12];
    const float f12 = sk[11] * c[9]  * c[1];
    const float f13 = sk[12] * c[13];
    const float f14 = sk[13] * c[0]  * c[5];
    const float f15 = sk[14] * c[2];
    const float f16 = sk[15] * c[3];
    const float f17 = sk[16] * c[3];
    const float f18 = sk[17] * c[15];
    const float f19 = sk[18] * c[15];
    const float f20 = sk[19] * c[16] * c[5];
    const float f21 = sk[20] * c[18];
    const float f22 = sk[21] * c[18];
    const float f23 = sk[22] * c[0]  * c[3];
    const float f24 = sk[23] * c[18] * c[0];
    const float f25 = sk[24] * c[19];

    float dy[20];
    dy[0]  = -f1 - f10 - f14 - f23 - f24 + f2 + f3 + f9 + f11 + f12 + f22 + f25;
    dy[1]  = -f2 - f3 - f9 - f12 + f1 + f21;
    dy[2]  = -f15 + f1 + f17 + f19 + f22;
    dy[3]  = -f2 - f16 - f17 - f23 + f15;
    dy[4]  = -f3 + 2.0f * f4 + f6 + f7 + f13 + f20;
    dy[5]  = -f6 - f8 - f14 - f20 + f3 + 2.0f * f18;
    dy[6]  = -f4 - f5 - f6 + f13;
    dy[7]  =  f4 + f5 + f6 + f7;
    dy[8]  = -f7 - f8;
    dy[9]  = -f12 + f7 + f9;
    dy[10] = -f9 - f10 + f8 + f11;
    dy[11] =  f9;
    dy[12] = -f11 + f10;
    dy[13] = -f13 + f12;
    dy[14] =  f14;
    dy[15] = -f18 - f19 + f16;
    dy[16] = -f20;
    dy[17] =  f20;
    dy[18] = -f21 - f22 - f24 + f23 + f25;
    dy[19] = -f25 + f24;

    // Transpose into padded out-tile: addr = t*21 + s, 21 coprime 32 -> conflict-free.
#pragma unroll
    for (int s = 0; s < 20; ++s) lds[t * PAD + s] = dy[s];
    __syncthreads();

    // Dense store phase: block covers 256*20 floats = 1280 float4s.
    // Each output float4 J holds floats of exactly one column (20 % 4 == 0):
    // column q = J/5, starting species r = 4*(J%5) -> contiguous in LDS.
    float4* outv = (float4*)out;
    const int blockBaseF4 = blockIdx.x * 1280;
    const int nF4 = nvalid * 5;
#pragma unroll
    for (int i = 0; i < 5; ++i) {
        const int J = i * 256 + t;
        if (J < nF4) {
            const int q = J / 5;
            const int r = 4 * (J % 5);
            const float* p = &lds[q * PAD + r];
            outv[blockBaseF4 + J] = make_float4(p[0], p[1], p[2], p[3]);
        }
    }
}

extern "C" void kernel_launch(void* const* d_in, const int* in_sizes, int n_in,
                              void* d_out, int out_size, void* d_ws, size_t ws_size,
                              hipStream_t stream) {
    // d_in[0] = t (unused), d_in[1] = conc_in [20, B], d_in[2] = k [25]
    const float* conc = (const float*)d_in[1];
    const float* k    = (const float*)d_in[2];
    float* out        = (float*)d_out;

    const int block = 256;
    const int grid  = (B_TOTAL + block - 1) / block;
    pollu_kernel<<<grid, block, 0, stream>>>(conc, k, out);
}

// Round 2
// 277.278 us; speedup vs baseline: 1.0156x; 1.0156x over previous
//
#include <hip/hip_runtime.h>

#define B_TOTAL 2000000
#define RS 260    // chunk row stride (floats); multiple of 4 -> 16B-aligned b128 LDS writes
#define CPB 1024  // columns per block (256 threads x 4 cols/thread)

// POLLU RHS: 25 fluxes, 20 species.
// conc: [20, B] species-major; out: [B, 20].
// v3: 4 columns/thread. Loads are float4 straight to VGPRs (1KB/wave-instr,
//     no LDS round-trip). dy overwrites c4 in place. Output transposed through
//     one species-major [20][RS] LDS chunk in 4 per-wave passes:
//     write = 20x contiguous ds_write_b128 (conflict-free, no repack),
//     read  = dense float4 sweep to global (full-line stores).
__global__ __launch_bounds__(256) void pollu_kernel(
    const float* __restrict__ conc,
    const float* __restrict__ k,
    float* __restrict__ out)
{
    __shared__ __align__(16) float lds[20 * RS];  // 20800 B

    const int t = threadIdx.x;
    const int base = blockIdx.x * CPB;
    const int ncols = min(CPB, B_TOTAL - base);

    // k is uniform + constant-indexed -> scalar (SGPR) loads, no LDS, no barrier.
    const float k0 = k[0],  k1 = k[1],  k2 = k[2],  k3 = k[3],  k4 = k[4];
    const float k5 = k[5],  k6 = k[6],  k7 = k[7],  k8 = k[8],  k9 = k[9];
    const float k10 = k[10], k11 = k[11], k12 = k[12], k13 = k[13], k14 = k[14];
    const float k15 = k[15], k16 = k[16], k17 = k[17], k18 = k[18], k19 = k[19];
    const float k20 = k[20], k21 = k[21], k22 = k[22], k23 = k[23], k24 = k[24];

// Compute 25 fluxes from C(s), then overwrite C(s) with dy[s].
// Safe in-place: every C read happens in the flux block, before any C write.
#define POLLU_FLUX_DY(C)                                                      \
        const float f1  = k0  * C(0);                                         \
        const float f2  = k1  * C(1)  * C(3);                                 \
        const float f3  = k2  * C(4)  * C(1);                                 \
        const float f4  = k3  * C(6);                                         \
        const float f5  = k4  * C(6);                                         \
        const float f6  = k5  * C(6)  * C(5);                                 \
        const float f7  = k6  * C(8);                                         \
        const float f8  = k7  * C(8)  * C(5);                                 \
        const float f9  = k8  * C(10) * C(1);                                 \
        const float f10 = k9  * C(10) * C(0);                                 \
        const float f11 = k10 * C(12);                                        \
        const float f12 = k11 * C(9)  * C(1);                                 \
        const float f13 = k12 * C(13);                                        \
        const float f14 = k13 * C(0)  * C(5);                                 \
        const float f15 = k14 * C(2);                                         \
        const float f16 = k15 * C(3);                                         \
        const float f17 = k16 * C(3);                                         \
        const float f18 = k17 * C(15);                                        \
        const float f19 = k18 * C(15);                                        \
        const float f20 = k19 * C(16) * C(5);                                 \
        const float f21 = k20 * C(18);                                        \
        const float f22 = k21 * C(18);                                        \
        const float f23 = k22 * C(0)  * C(3);                                 \
        const float f24 = k23 * C(18) * C(0);                                 \
        const float f25 = k24 * C(19);                                        \
        C(0)  = -f1 - f10 - f14 - f23 - f24 + f2 + f3 + f9 + f11 + f12 + f22 + f25; \
        C(1)  = -f2 - f3 - f9 - f12 + f1 + f21;                               \
        C(2)  = -f15 + f1 + f17 + f19 + f22;                                  \
        C(3)  = -f2 - f16 - f17 - f23 + f15;                                  \
        C(4)  = -f3 + 2.0f * f4 + f6 + f7 + f13 + f20;                        \
        C(5)  = -f6 - f8 - f14 - f20 + f3 + 2.0f * f18;                       \
        C(6)  = -f4 - f5 - f6 + f13;                                          \
        C(7)  =  f4 + f5 + f6 + f7;                                           \
        C(8)  = -f7 - f8;                                                     \
        C(9)  = -f12 + f7 + f9;                                               \
        C(10) = -f9 - f10 + f8 + f11;                                         \
        C(11) =  f9;                                                          \
        C(12) = -f11 + f10;                                                   \
        C(13) = -f13 + f12;                                                   \
        C(14) =  f14;                                                         \
        C(15) = -f18 - f19 + f16;                                             \
        C(16) = -f20;                                                         \
        C(17) =  f20;                                                         \
        C(18) = -f21 - f22 - f24 + f23 + f25;                                 \
        C(19) = -f25 + f24;

#define CX(s) c4[s].x
#define CY(s) c4[s].y
#define CZ(s) c4[s].z
#define CW(s) c4[s].w
#define CA(s) c[s]

    if (ncols == CPB) {
        // ---- load: 20 x global_load_dwordx4, each wave reads 1KB contiguous ----
        float4 c4[20];
        const size_t off = (size_t)base + (size_t)(4 * t);
#pragma unroll
        for (int s = 0; s < 20; ++s)
            c4[s] = *(const float4*)(conc + (size_t)s * B_TOTAL + off);

        // ---- compute: dy overwrites c4 component-wise (compile-time components) ----
        { POLLU_FLUX_DY(CX) }
        { POLLU_FLUX_DY(CY) }
        { POLLU_FLUX_DY(CZ) }
        { POLLU_FLUX_DY(CW) }

        // ---- store: 4 passes; pass p = wave p's 256 columns ----
        float4* outv = (float4*)out;
        const int wave = t >> 6;
        const int lane = t & 63;
#pragma unroll
        for (int p = 0; p < 4; ++p) {
            __syncthreads();  // chunk free (prev pass's reads done)
            if (wave == p) {
                // 20x ds_write_b128, lanes contiguous (16B*64=1KB) -> conflict-free.
                // c4[s] already holds dy for this thread's 4 adjacent columns.
#pragma unroll
                for (int s = 0; s < 20; ++s)
                    *(float4*)&lds[s * RS + 4 * lane] = c4[s];
            }
            __syncthreads();  // chunk filled
            // 1280 float4s = 256 columns x 20 species, dense full-line stores.
            const int passBase = blockIdx.x * 5120 + p * 1280;
#pragma unroll
            for (int i = 0; i < 5; ++i) {
                const int J = i * 256 + t;
                const int q = J / 5;        // chunk-local column
                const int r = 4 * (J % 5);  // starting species
                outv[passBase + J] = make_float4(lds[(r + 0) * RS + q],
                                                 lds[(r + 1) * RS + q],
                                                 lds[(r + 2) * RS + q],
                                                 lds[(r + 3) * RS + q]);
            }
        }
    } else {
        // ---- tail block (128 columns once): scalar fallback, no barriers ----
        for (int col = base + t; col < B_TOTAL; col += 256) {
            float c[20];
#pragma unroll
            for (int s = 0; s < 20; ++s) c[s] = conc[(size_t)s * B_TOTAL + (size_t)col];
            { POLLU_FLUX_DY(CA) }
#pragma unroll
            for (int s = 0; s < 20; ++s) out[(size_t)col * 20 + s] = c[s];
        }
    }
}

extern "C" void kernel_launch(void* const* d_in, const int* in_sizes, int n_in,
                              void* d_out, int out_size, void* d_ws, size_t ws_size,
                              hipStream_t stream) {
    // d_in[0] = t (unused), d_in[1] = conc_in [20, B], d_in[2] = k [25]
    const float* conc = (const float*)d_in[1];
    const float* k    = (const float*)d_in[2];
    float* out        = (float*)d_out;

    const int block = 256;
    const int grid  = (B_TOTAL + CPB - 1) / CPB;  // 1954
    pollu_kernel<<<grid, block, 0, stream>>>(conc, k, out);
}